// Round 13
// baseline (129.436 us; speedup 1.0000x reference)
//
#include <hip/hip_runtime.h>
#include <hip/hip_bf16.h>

// out[b,d,r] = sum_c p[b,c] * softmax_d( x[b,:] @ W[:, c*8+d, r] + bias[c,d,r] )
// B=16384, F=128, C=8, R=64.  bf16 MFMA 16x16x32, fully fused.
//
// R22->R23: scheduling levers exhausted (R16/R21/R22 all neutral); fused
// time matches the PIPE-SUM (LDS 6.2k + MFMA 2.5k + VALU 1.0k /c) ->
// only total-byte reduction helps.  The byte-halver at full occupancy is
// R12's m=2 [2d x 8r] packing (each B-fragment ds_read feeds 2 MFMAs;
// 16 waves/CU via 8 r8-chunks) -- and R12's 47us was POISONED by the
// R20-class bug: stage(c+1) issued BEFORE p/bias, and bias is the MFMA
// C-in consumed first -> its wait = vmcnt(0) -> drained the fresh stage
// every c (8x exposed L2 latency, no prefetch).  R23 re-tests the layout
// fairly:
//  - load order per c: p (8) and biasT (4) FIRST, stage(c+1) LAST ->
//    waiting on bias leaves the 4 stage loads in flight.
//  - t-outer MFMA (4 independent [2d]-pair chains x m=2) with exp2 fused
//    per-t; softmax d-sum = 3 adds + ONE shfl_xor(8) per (m,jj).
//  - LOG2E prefolded (wf, biasT); one barrier/c; ring-2 x 16KB; w-major
//    grid (XCD = g%8); nontemporal stores (32B segments accepted: HBM at
//    21% -- isolates the LDS question from the store question).
// LDS reads/CU/c: 256KB (vs R18's 512KB) at unchanged 16 waves/CU.

#define F_DIM    128
#define NCOL     4096      // C*C*R
#define OUT_STRIDE 512     // C*R
#define LOG2E    1.44269504088896340736f

typedef __bf16 bf16x8 __attribute__((ext_vector_type(8)));
typedef float  f32x4  __attribute__((ext_vector_type(4)));

#define AS1(p) ((const __attribute__((address_space(1))) unsigned int*)(p))
#define AS3(p) ((__attribute__((address_space(3))) unsigned int*)(p))

// ---------------------------------------------------------------------------
// Prepass (layout VERIFIED in R11/R12): W fp32 (128 x 4096) -> bf16 MFMA
// B-fragments, pre-scaled by log2(e).
// Fragment gf = ((c*4 + t)*8 + w)*4 + kk covers the 16 columns
//   n(l15) = c*512 + (2t + (l15>>3))*64 + w*8 + (l15&7)
// (the d = 2t+h pair for r8-chunk w), with k = kk*32 + (lane>>4)*8 + j in
// element j of the lane's bf16x8.  Also biasT[(c*64+r)*8+d] = bias*log2e.
// ---------------------------------------------------------------------------
__global__ void wconv_kernel(const float* __restrict__ W,
                             const float* __restrict__ bias,
                             __bf16* __restrict__ wf,
                             float* __restrict__ biasT) {
    int f    = blockIdx.x * 256 + threadIdx.x;  // 0..65535
    int lane = f & 63;
    int gf   = f >> 6;          // fragment id 0..1023
    int kk   = gf & 3;
    int w    = (gf >> 2) & 7;
    int t    = (gf >> 5) & 3;
    int c    = gf >> 7;
    int l15  = lane & 15;
    int kbase = kk * 32 + (lane >> 4) * 8;
    int col   = c * 512 + (2 * t + (l15 >> 3)) * 64 + w * 8 + (l15 & 7);
    bf16x8 frag;
#pragma unroll
    for (int j = 0; j < 8; ++j)
        frag[j] = (__bf16)(W[(kbase + j) * NCOL + col] * LOG2E);
    *(bf16x8*)(wf + (size_t)f * 8) = frag;

    if (f < 4096) {   // biasT: [c][r][d]
        int c2 = f >> 9, r = (f >> 3) & 63, d = f & 7;
        biasT[f] = bias[(c2 * 8 + d) * 64 + r] * LOG2E;
    }
}

// ---------------------------------------------------------------------------
// Fused GEMM + bias + softmax(d) + p-contraction.
// Block: 256 thr (4 waves), 128 batch rows, one r8-chunk w = blockIdx>>7.
// Wave ww owns rows b0..b0+32 (m=2: every B ds_read feeds 2 MFMAs).
// Per c: 16 fragments (4 t x 4 kk, 16 KB) ring-2 staged (wave ww stages
// t=ww's 4 kk frags), block-shared.  t-outer MFMA with exp2 fused per-t;
// softmax d-sum: 3 in-lane adds + 1 shfl_xor(8) merging the h halves.
// C/D layout: col=lane&15 -> (h = d LSB, q = r within chunk),
// row = quad*4+jj -> batch row.
// ---------------------------------------------------------------------------
__global__ __launch_bounds__(256, 4)
void fused_kernel(const float* __restrict__ x, const float* __restrict__ p,
                  const float* __restrict__ biasT, const __bf16* __restrict__ wf,
                  float* __restrict__ out) {
    __shared__ __align__(16) char lds[32768];   // 2 x (16 fragments = 16 KB)

    const int lane = threadIdx.x & 63;
    const int ww   = threadIdx.x >> 6;   // wave 0..3 (= staged t)
    const int quad = lane >> 4;
    const int l15  = lane & 15;
    const int h    = l15 >> 3;           // d LSB
    const int q    = l15 & 7;            // r within chunk
    const int w    = blockIdx.x >> 7;    // r8-chunk 0..7 (w-major: XCD = g%8)
    const int g    = blockIdx.x & 127;   // row-group
    const int b0   = g * 128 + ww * 32;

    // ---- prologue: stage c=0 into ring slot 0 (wave ww stages t=ww) -------
    {
        const __bf16* src = wf + (size_t)((ww * 8 + w) * 4) * 512 + lane * 8;
#pragma unroll
        for (int kk = 0; kk < 4; ++kk)
            __builtin_amdgcn_global_load_lds(
                AS1(src + kk * 512),
                AS3(lds + (ww * 4 + kk) * 1024), 16, 0, 0);
    }

    // A fragments: afr[m][kk][j] = x_bf16[b0+m*16+l15][kk*32 + quad*8 + j]
    bf16x8 afr[2][4];
#pragma unroll
    for (int m = 0; m < 2; ++m) {
        const float* xr = x + (size_t)(b0 + m * 16 + l15) * F_DIM + quad * 8;
#pragma unroll
        for (int kk = 0; kk < 4; ++kk) {
            float4 lo = *(const float4*)(xr + kk * 32);
            float4 hi = *(const float4*)(xr + kk * 32 + 4);
            bf16x8 f;
            f[0] = (__bf16)lo.x; f[1] = (__bf16)lo.y;
            f[2] = (__bf16)lo.z; f[3] = (__bf16)lo.w;
            f[4] = (__bf16)hi.x; f[5] = (__bf16)hi.y;
            f[6] = (__bf16)hi.z; f[7] = (__bf16)hi.w;
            afr[m][kk] = f;
        }
    }

    float O[2][4][4] = {};   // [m][t][jj] output accumulator over c

#pragma unroll 1
    for (int c = 0; c < 8; ++c) {
        // barrier: stage(c) landed (issued a full phase ago, implicit
        // vmcnt(0)) AND all waves done reading ring[(c+1)&1].
        __syncthreads();

        // ---- p and biasT FIRST: their pre-MFMA waits must leave the
        // stage(c+1) loads (issued after) outstanding. ----------------------
        float pvv[2][4];
#pragma unroll
        for (int m = 0; m < 2; ++m)
#pragma unroll
            for (int jj = 0; jj < 4; ++jj)
                pvv[m][jj] = p[(size_t)(b0 + m * 16 + quad * 4 + jj) * 8 + c];

        float bvl[4];
#pragma unroll
        for (int t = 0; t < 4; ++t)
            bvl[t] = biasT[(c * 64 + w * 8 + q) * 8 + 2 * t + h];

        // ---- issue stage(c+1) LAST (stays in flight through compute) ------
        if (c < 7) {
            const __bf16* src =
                wf + (size_t)((((c + 1) * 4 + ww) * 8 + w) * 4) * 512 + lane * 8;
            char* dst = lds + ((c + 1) & 1) * 16384;
#pragma unroll
            for (int kk = 0; kk < 4; ++kk)
                __builtin_amdgcn_global_load_lds(
                    AS1(src + kk * 512),
                    AS3(dst + (ww * 4 + kk) * 1024), 16, 0, 0);
        }

        // ---- t-outer MFMA (m=2 per fragment) with exp2 fused per-t --------
        const char* buf = lds + (c & 1) * 16384;
        f32x4 e[2][4];
#pragma unroll
        for (int t = 0; t < 4; ++t) {
            f32x4 a0 = {bvl[t], bvl[t], bvl[t], bvl[t]};   // C-in = bias
            f32x4 a1 = a0;
#pragma unroll
            for (int kk = 0; kk < 4; ++kk) {
                bf16x8 bfr = *(const bf16x8*)(buf + (t * 4 + kk) * 1024 + lane * 16);
                a0 = __builtin_amdgcn_mfma_f32_16x16x32_bf16(afr[0][kk], bfr, a0, 0, 0, 0);
                a1 = __builtin_amdgcn_mfma_f32_16x16x32_bf16(afr[1][kk], bfr, a1, 0, 0, 0);
            }
#pragma unroll
            for (int jj = 0; jj < 4; ++jj) {
                a0[jj] = __builtin_amdgcn_exp2f(a0[jj]);
                a1[jj] = __builtin_amdgcn_exp2f(a1[jj]);
            }
            e[0][t] = a0;
            e[1][t] = a1;
        }

        // ---- softmax over d + p-weighted accumulate -----------------------
#pragma unroll
        for (int m = 0; m < 2; ++m) {
#pragma unroll
            for (int jj = 0; jj < 4; ++jj) {
                float s4 = (e[m][0][jj] + e[m][1][jj])
                         + (e[m][2][jj] + e[m][3][jj]);   // this h's 4 d's
                float s8 = s4 + __shfl_xor(s4, 8, 64);    // + other h's 4 d's
                float scale = pvv[m][jj] * __builtin_amdgcn_rcpf(s8);
#pragma unroll
                for (int t = 0; t < 4; ++t)
                    O[m][t][jj] = __builtin_fmaf(e[m][t][jj], scale, O[m][t][jj]);
            }
        }
        // no second barrier: next iteration's __syncthreads covers the WAR
        // hazard on ring[(c+1)&1].
    }

    // ---- stores: out[b, (2t+h)*64 + w*8 + q] — 32B segments, nontemporal --
#pragma unroll
    for (int m = 0; m < 2; ++m)
#pragma unroll
        for (int jj = 0; jj < 4; ++jj) {
            float* orow = out + (size_t)(b0 + m * 16 + quad * 4 + jj) * OUT_STRIDE
                          + h * 64 + w * 8 + q;
#pragma unroll
            for (int t = 0; t < 4; ++t)
                __builtin_nontemporal_store(O[m][t][jj], orow + t * 128);
        }
}

extern "C" void kernel_launch(void* const* d_in, const int* in_sizes, int n_in,
                              void* d_out, int out_size, void* d_ws, size_t ws_size,
                              hipStream_t stream) {
    const float* x    = (const float*)d_in[0];   // (16384, 128)
    const float* p    = (const float*)d_in[1];   // (16384, 8)
    const float* W    = (const float*)d_in[2];   // (128, 64, 64)
    const float* bias = (const float*)d_in[3];   // (8, 8, 64)
    float* out = (float*)d_out;                  // (16384, 8, 64)
    __bf16* wf    = (__bf16*)d_ws;               // 1 MB bf16 fragments
    float*  biasT = (float*)((char*)d_ws + (1 << 20));  // 16 KB scaled bias

    wconv_kernel<<<dim3(256), dim3(256), 0, stream>>>(W, bias, wf, biasT);
    fused_kernel<<<dim3(1024), dim3(256), 0, stream>>>(x, p, biasT, wf, out);
}